// Round 1
// baseline (467.490 us; speedup 1.0000x reference)
//
#include <hip/hip_runtime.h>
#include <cstdint>
#include <cstddef>

#define NROWS 4096
#define DO 512
#define DH 1024
#define KNN 10

typedef __bf16 bf16;
typedef __bf16 bf16x4 __attribute__((ext_vector_type(4)));
typedef __bf16 bf16x8 __attribute__((ext_vector_type(8)));
typedef float f32x4 __attribute__((ext_vector_type(4)));

// ---------- ws layout ----------
constexpr size_t OFF_SQO  = 0;                       // 4096 * 4      = 16384
constexpr size_t OFF_TOPK = 16384;                   // 4096 * 16 * 4 = 262144
constexpr size_t OFF_ASUM = 278528;                  // 256 bytes reserved
constexpr size_t OFF_MASK = 278784;                  // 4096 * 128 * 4 = 2097152
constexpr size_t OFF_SIM  = 2375936;                 // 4096 * 1024 * 2 = 8388608
// total ~10.8 MB

// ---------- K0a: row squared norms of `original` ----------
__global__ __launch_bounds__(256) void rownorm_orig_k(const float* __restrict__ x,
                                                      float* __restrict__ sqo) {
  int row = blockIdx.x;
  int tid = threadIdx.x;
  const float* p = x + (size_t)row * DO;
  float2 v = ((const float2*)p)[tid];           // 512 / 256 = 2 per thread
  float s = v.x * v.x + v.y * v.y;
  __shared__ float red[256];
  red[tid] = s; __syncthreads();
  for (int off = 128; off > 0; off >>= 1) {
    if (tid < off) red[tid] += red[tid + off];
    __syncthreads();
  }
  if (tid == 0) sqo[row] = red[0];
}

// ---------- K0b: normalize `hidden` rows -> bf16 sim matrix ----------
__global__ __launch_bounds__(256) void normalize_hidden_k(const float* __restrict__ h,
                                                          bf16* __restrict__ sim) {
  int row = blockIdx.x;
  int tid = threadIdx.x;
  const float* p = h + (size_t)row * DH;
  float4 v = ((const float4*)p)[tid];           // 1024 / 256 = 4 per thread
  float s = v.x * v.x + v.y * v.y + v.z * v.z + v.w * v.w;
  __shared__ float red[256];
  red[tid] = s; __syncthreads();
  for (int off = 128; off > 0; off >>= 1) {
    if (tid < off) red[tid] += red[tid + off];
    __syncthreads();
  }
  float scale = 1.0f / fmaxf(sqrtf(red[0]), 1e-12f);
  bf16x4 o;
  o[0] = (bf16)(v.x * scale);
  o[1] = (bf16)(v.y * scale);
  o[2] = (bf16)(v.z * scale);
  o[3] = (bf16)(v.w * scale);
  ((bf16x4*)(sim + (size_t)row * DH))[tid] = o;
}

// ---------- K2: fp32 SGEMM (A A^T) -> clamped squared distances ----------
#define BM 128
#define BK 32
__global__ __launch_bounds__(256, 4) void sgemm_d2_k(const float* __restrict__ A,
                                                     const float* __restrict__ sqo,
                                                     float* __restrict__ D2) {
  __shared__ float As[BK][BM + 4];   // +4 keeps rows 16B-aligned (132*4=528)
  __shared__ float Bs[BK][BM + 4];
  int bj = blockIdx.x, bi = blockIdx.y;
  int row0 = bi * BM, col0 = bj * BM;
  int tid = threadIdx.x;
  int tx = tid & 15, ty = tid >> 4;

  float acc[8][8];
#pragma unroll
  for (int i = 0; i < 8; ++i) {
#pragma unroll
    for (int j = 0; j < 8; ++j) acc[i][j] = 0.0f;
  }

  for (int kt = 0; kt < DO; kt += BK) {
#pragma unroll
    for (int e = 0; e < 4; ++e) {
      int q = tid + e * 256;                 // 0..1023 float4 units
      int r = q >> 3, kq = q & 7;            // 8 float4 per 32-float row slice
      float4 va = *(const float4*)(A + (size_t)(row0 + r) * DO + kt + kq * 4);
      float4 vb = *(const float4*)(A + (size_t)(col0 + r) * DO + kt + kq * 4);
      As[kq * 4 + 0][r] = va.x; As[kq * 4 + 1][r] = va.y;
      As[kq * 4 + 2][r] = va.z; As[kq * 4 + 3][r] = va.w;
      Bs[kq * 4 + 0][r] = vb.x; Bs[kq * 4 + 1][r] = vb.y;
      Bs[kq * 4 + 2][r] = vb.z; Bs[kq * 4 + 3][r] = vb.w;
    }
    __syncthreads();
#pragma unroll
    for (int k = 0; k < BK; ++k) {
      float a[8], b[8];
      *(float4*)&a[0] = *(const float4*)&As[k][ty * 8];
      *(float4*)&a[4] = *(const float4*)&As[k][ty * 8 + 4];
      *(float4*)&b[0] = *(const float4*)&Bs[k][tx * 8];
      *(float4*)&b[4] = *(const float4*)&Bs[k][tx * 8 + 4];
#pragma unroll
      for (int i = 0; i < 8; ++i) {
#pragma unroll
        for (int j = 0; j < 8; ++j) acc[i][j] = fmaf(a[i], b[j], acc[i][j]);
      }
    }
    __syncthreads();
  }

  float sqi[8], sqj[8];
#pragma unroll
  for (int i = 0; i < 8; ++i) sqi[i] = sqo[row0 + ty * 8 + i];
#pragma unroll
  for (int j = 0; j < 8; ++j) sqj[j] = sqo[col0 + tx * 8 + j];
#pragma unroll
  for (int i = 0; i < 8; ++i) {
    float* dst = D2 + (size_t)(row0 + ty * 8 + i) * NROWS + col0 + tx * 8;
    float4 o0, o1;
    o0.x = fmaxf(sqi[i] + sqj[0] - 2.0f * acc[i][0], 0.0f);
    o0.y = fmaxf(sqi[i] + sqj[1] - 2.0f * acc[i][1], 0.0f);
    o0.z = fmaxf(sqi[i] + sqj[2] - 2.0f * acc[i][2], 0.0f);
    o0.w = fmaxf(sqi[i] + sqj[3] - 2.0f * acc[i][3], 0.0f);
    o1.x = fmaxf(sqi[i] + sqj[4] - 2.0f * acc[i][4], 0.0f);
    o1.y = fmaxf(sqi[i] + sqj[5] - 2.0f * acc[i][5], 0.0f);
    o1.z = fmaxf(sqi[i] + sqj[6] - 2.0f * acc[i][6], 0.0f);
    o1.w = fmaxf(sqi[i] + sqj[7] - 2.0f * acc[i][7], 0.0f);
    *(float4*)dst       = o0;
    *(float4*)(dst + 4) = o1;
  }
}

// ---------- K3: per-row top-10 (stable-sort order) ----------
__global__ __launch_bounds__(256) void topk_k(const float* __restrict__ D2,
                                              int* __restrict__ topk) {
  int row = blockIdx.x;
  int tid = threadIdx.x;
  const float* p = D2 + (size_t)row * NROWS;

  unsigned long long lst[KNN];
#pragma unroll
  for (int t = 0; t < KNN; ++t) lst[t] = ~0ULL;

  auto consider = [&](float val, int j) {
    unsigned long long key =
        ((unsigned long long)__float_as_uint(val) << 32) | (unsigned)j;
    if (key < lst[KNN - 1]) {
      lst[KNN - 1] = key;
#pragma unroll
      for (int t = KNN - 1; t > 0; --t) {
        if (lst[t] < lst[t - 1]) {
          unsigned long long tmp = lst[t]; lst[t] = lst[t - 1]; lst[t - 1] = tmp;
        }
      }
    }
  };

  for (int s = 0; s < 4; ++s) {
    int q = tid + s * 256;                    // float4 index
    float4 v = *(const float4*)(p + q * 4);
    consider(v.x, q * 4 + 0);
    consider(v.y, q * 4 + 1);
    consider(v.z, q * 4 + 2);
    consider(v.w, q * 4 + 3);
  }

  __shared__ unsigned long long red[256];
  for (int s = 0; s < KNN; ++s) {
    unsigned long long mykey = lst[0];
    red[tid] = mykey;
    __syncthreads();
    for (int off = 128; off > 0; off >>= 1) {
      if (tid < off) {
        unsigned long long o = red[tid + off];
        if (o < red[tid]) red[tid] = o;
      }
      __syncthreads();
    }
    unsigned long long w = red[0];
    if (tid == 0) topk[row * 16 + s] = (int)(w & 0xFFFFFFFFULL);
    if (mykey == w) {                         // winner pops its head (static shift)
#pragma unroll
      for (int t = 0; t < KNN - 1; ++t) lst[t] = lst[t + 1];
      lst[KNN - 1] = ~0ULL;
    }
    __syncthreads();
  }
}

// ---------- K4: symmetrized anchor bitmask ----------
__global__ void build_mask_k(const int* __restrict__ topk,
                             unsigned int* __restrict__ mask) {
  int i = blockIdx.x;
  int t = threadIdx.x;
  if (t < KNN) {
    int j = topk[i * 16 + t];
    atomicOr(mask + (size_t)i * (NROWS / 32) + (j >> 5), 1u << (j & 31));
    atomicOr(mask + (size_t)j * (NROWS / 32) + (i >> 5), 1u << (i & 31));
  }
}

// ---------- K4c: popcount -> a_sum ----------
__global__ __launch_bounds__(256) void popcnt_k(const unsigned int* __restrict__ mask,
                                                int* __restrict__ a_sum) {
  int tid = blockIdx.x * 256 + threadIdx.x;
  int stride = gridDim.x * 256;
  int cnt = 0;
  for (int q = tid; q < NROWS * (NROWS / 32); q += stride) cnt += __popc(mask[q]);
  for (int off = 32; off > 0; off >>= 1) cnt += __shfl_down(cnt, off);
  __shared__ int wsum[4];
  int lane = threadIdx.x & 63, wv = threadIdx.x >> 6;
  if (lane == 0) wsum[wv] = cnt;
  __syncthreads();
  if (threadIdx.x == 0) atomicAdd(a_sum, wsum[0] + wsum[1] + wsum[2] + wsum[3]);
}

// ---------- K5: bf16 MFMA GEMM (S S^T) -> cosine matrix ----------
__device__ __forceinline__ void gld_lds16(const void* g, void* l) {
  __builtin_amdgcn_global_load_lds(
      (const __attribute__((address_space(1))) unsigned int*)g,
      (__attribute__((address_space(3))) unsigned int*)l, 16, 0, 0);
}

__global__ __launch_bounds__(256) void gemm_cos_k(const bf16* __restrict__ S,
                                                  float* __restrict__ C) {
  __shared__ bf16 Asm[128 * 32];
  __shared__ bf16 Bsm[128 * 32];
  int bj = blockIdx.x, bi = blockIdx.y;
  int row0 = bi * 128, col0 = bj * 128;
  int tid = threadIdx.x;
  int wave = tid >> 6, lane = tid & 63;
  int wr = wave >> 1, wc = wave & 1;          // 2x2 waves, 64x64 each
  int lr = lane & 15, lk = lane >> 4;

  f32x4 acc[4][4];
#pragma unroll
  for (int m = 0; m < 4; ++m) {
#pragma unroll
    for (int n = 0; n < 4; ++n) acc[m][n] = f32x4{0.f, 0.f, 0.f, 0.f};
  }

  for (int kt = 0; kt < DH; kt += 32) {
#pragma unroll
    for (int c = 0; c < 2; ++c) {
      int idx = tid + c * 256;                // 16B units; 4 per 32-elem row slice
      int r = idx >> 2, kq = idx & 3;
      // LDS dest is wave-uniform base + lane*16 (HW behavior)
      gld_lds16(S + (size_t)(row0 + r) * DH + kt + kq * 8,
                Asm + ((size_t)c * 256 + (size_t)wave * 64) * 8);
      gld_lds16(S + (size_t)(col0 + r) * DH + kt + kq * 8,
                Bsm + ((size_t)c * 256 + (size_t)wave * 64) * 8);
    }
    __syncthreads();

    bf16x8 af[4], bfr[4];
#pragma unroll
    for (int m = 0; m < 4; ++m) {
      af[m]  = *(const bf16x8*)&Asm[(wr * 64 + m * 16 + lr) * 32 + lk * 8];
      bfr[m] = *(const bf16x8*)&Bsm[(wc * 64 + m * 16 + lr) * 32 + lk * 8];
    }
#pragma unroll
    for (int m = 0; m < 4; ++m) {
#pragma unroll
      for (int n = 0; n < 4; ++n)
        acc[m][n] = __builtin_amdgcn_mfma_f32_16x16x32_bf16(af[m], bfr[n],
                                                            acc[m][n], 0, 0, 0);
    }
    __syncthreads();
  }

  // C/D layout: col = lane&15, row = (lane>>4)*4 + reg   [verified m89/m91]
#pragma unroll
  for (int m = 0; m < 4; ++m) {
#pragma unroll
    for (int n = 0; n < 4; ++n) {
      int col = col0 + wc * 64 + n * 16 + lr;
#pragma unroll
      for (int g = 0; g < 4; ++g) {
        int rrow = row0 + wr * 64 + m * 16 + lk * 4 + g;
        C[(size_t)rrow * NROWS + col] = acc[m][n][g];
      }
    }
  }
}

// ---------- K6: masked scaling into both outputs (in place) ----------
__global__ __launch_bounds__(256) void finalize_k(float* __restrict__ Cm,
                                                  float* __restrict__ Aout,
                                                  const unsigned int* __restrict__ mask,
                                                  const int* __restrict__ a_sum_p) {
  size_t idx = (size_t)blockIdx.x * 256 + threadIdx.x;   // one float4 each
  int i  = (int)(idx >> 10);                              // 1024 float4 per row
  int jq = (int)(idx & 1023);
  float asum = (float)(*a_sum_p);
  float Nw = 0.5f / asum;                                 // (1-ALPHA)/a_sum
  float Nb = 1.0f / (16777216.0f - 2.0f * asum);          // 1/(N*N - 2*a_sum)
  unsigned int mw = mask[(size_t)i * (NROWS / 32) + (jq >> 3)];
  int b0 = (jq & 7) * 4;
  float4 c = ((const float4*)Cm)[idx];
  float4 na, aa;
  { unsigned a = (mw >> (b0 + 0)) & 1u; na.x = a ? 0.f : Nb * c.x; aa.x = a ? Nw * c.x : 0.f; }
  { unsigned a = (mw >> (b0 + 1)) & 1u; na.y = a ? 0.f : Nb * c.y; aa.y = a ? Nw * c.y : 0.f; }
  { unsigned a = (mw >> (b0 + 2)) & 1u; na.z = a ? 0.f : Nb * c.z; aa.z = a ? Nw * c.z : 0.f; }
  { unsigned a = (mw >> (b0 + 3)) & 1u; na.w = a ? 0.f : Nb * c.w; aa.w = a ? Nw * c.w : 0.f; }
  ((float4*)Cm)[idx]   = na;
  ((float4*)Aout)[idx] = aa;
}

extern "C" void kernel_launch(void* const* d_in, const int* in_sizes, int n_in,
                              void* d_out, int out_size, void* d_ws, size_t ws_size,
                              hipStream_t stream) {
  const float* original = (const float*)d_in[0];
  const float* hidden   = (const float*)d_in[1];
  float* out0 = (float*)d_out;                       // non_anchor_out (also C scratch)
  float* out1 = out0 + (size_t)NROWS * NROWS;        // anchor_out (also D2 scratch)

  char* ws = (char*)d_ws;
  float*        sqo   = (float*)(ws + OFF_SQO);
  int*          topk  = (int*)(ws + OFF_TOPK);
  int*          a_sum = (int*)(ws + OFF_ASUM);
  unsigned int* mask  = (unsigned int*)(ws + OFF_MASK);
  bf16*         sim   = (bf16*)(ws + OFF_SIM);

  rownorm_orig_k<<<NROWS, 256, 0, stream>>>(original, sqo);
  normalize_hidden_k<<<NROWS, 256, 0, stream>>>(hidden, sim);

  dim3 g32(NROWS / BM, NROWS / BM);
  sgemm_d2_k<<<g32, 256, 0, stream>>>(original, sqo, out1);

  topk_k<<<NROWS, 256, 0, stream>>>(out1, topk);

  hipMemsetAsync(ws + OFF_ASUM, 0, 256 + (size_t)NROWS * (NROWS / 32) * 4, stream);
  build_mask_k<<<NROWS, 64, 0, stream>>>(topk, mask);
  popcnt_k<<<512, 256, 0, stream>>>(mask, a_sum);

  dim3 gg(NROWS / 128, NROWS / 128);
  gemm_cos_k<<<gg, 256, 0, stream>>>(sim, out0);

  finalize_k<<<(NROWS / 4) * (NROWS / 256), 256, 0, stream>>>(out0, out1, mask, a_sum);
}

// Round 2
// 464.864 us; speedup vs baseline: 1.0056x; 1.0056x over previous
//
#include <hip/hip_runtime.h>
#include <cstdint>
#include <cstddef>

#define NROWS 4096
#define DO 512
#define DH 1024
#define KNN 10

typedef __bf16 bf16;
typedef __bf16 bf16x8 __attribute__((ext_vector_type(8)));
typedef float f32x4 __attribute__((ext_vector_type(4)));

// ---------- ws layout ----------
constexpr size_t OFF_SQO  = 0;                       // 4096 * 4      = 16384
constexpr size_t OFF_TOPK = 16384;                   // 4096 * 16 * 4 = 262144
constexpr size_t OFF_ASUM = 278528;                  // 256 bytes reserved
constexpr size_t OFF_MASK = 278784;                  // 4096 * 128 * 4 = 2097152
constexpr size_t OFF_SIM  = 2375936;                 // 4096 * 1024 * 2 = 8388608

__device__ __forceinline__ void gld_lds16(const void* g, void* l) {
  __builtin_amdgcn_global_load_lds(
      (const __attribute__((address_space(1))) unsigned int*)g,
      (__attribute__((address_space(3))) unsigned int*)l, 16, 0, 0);
}

// ---------- K0a: row squared norms of `original` ----------
__global__ __launch_bounds__(256) void rownorm_orig_k(const float* __restrict__ x,
                                                      float* __restrict__ sqo) {
  int row = blockIdx.x;
  int tid = threadIdx.x;
  const float* p = x + (size_t)row * DO;
  float2 v = ((const float2*)p)[tid];
  float s = v.x * v.x + v.y * v.y;
  __shared__ float red[256];
  red[tid] = s; __syncthreads();
  for (int off = 128; off > 0; off >>= 1) {
    if (tid < off) red[tid] += red[tid + off];
    __syncthreads();
  }
  if (tid == 0) sqo[row] = red[0];
}

// ---------- K0b: normalize `hidden` rows -> bf16 sim matrix ----------
__global__ __launch_bounds__(256) void normalize_hidden_k(const float* __restrict__ h,
                                                          bf16* __restrict__ sim) {
  int row = blockIdx.x;
  int tid = threadIdx.x;
  const float* p = h + (size_t)row * DH;
  float4 v = ((const float4*)p)[tid];
  float s = v.x * v.x + v.y * v.y + v.z * v.z + v.w * v.w;
  __shared__ float red[256];
  red[tid] = s; __syncthreads();
  for (int off = 128; off > 0; off >>= 1) {
    if (tid < off) red[tid] += red[tid + off];
    __syncthreads();
  }
  float scale = 1.0f / fmaxf(sqrtf(red[0]), 1e-12f);
  typedef __bf16 bf16x4_t __attribute__((ext_vector_type(4)));
  bf16x4_t o;
  o[0] = (bf16)(v.x * scale);
  o[1] = (bf16)(v.y * scale);
  o[2] = (bf16)(v.z * scale);
  o[3] = (bf16)(v.w * scale);
  ((bf16x4_t*)(sim + (size_t)row * DH))[tid] = o;
}

// ---------- K2: fp32 SGEMM (A A^T), symmetric, 64x64 tiles, dbuf LDS ----------
// LDS linear [64][32] f32 per tile; content swizzled via pre-swizzled global src:
// LDS slot s of row r holds global float4 (r, s ^ (r&7)).
__global__ __launch_bounds__(256) void sgemm_d2_k(const float* __restrict__ A,
                                                  const float* __restrict__ sqo,
                                                  float* __restrict__ D2) {
  __shared__ float As[2][64 * 32];
  __shared__ float Bs[2][64 * 32];
  int bj = blockIdx.x, bi = blockIdx.y;
  if (bi > bj) return;                       // symmetric: upper-tri tiles only
  int row0 = bi * 64, col0 = bj * 64;
  int tid = threadIdx.x;
  int tx = tid & 15, ty = tid >> 4;
  int wave = tid >> 6, l = tid & 63;
  int lh = l >> 3;                            // row-within-chunk
  int sslot = (l & 7) ^ lh;                   // swizzled source float4-slot
  int swa = ty & 7, swb = tx & 7;

  float acc[4][4];
#pragma unroll
  for (int i = 0; i < 4; ++i)
#pragma unroll
    for (int j = 0; j < 4; ++j) acc[i][j] = 0.0f;

  // prologue: stage tile 0 into buf 0
#pragma unroll
  for (int c = 0; c < 2; ++c) {
    int m = wave * 2 + c;                     // chunk 0..7 (8 rows each)
    gld_lds16(A + (size_t)(row0 + m * 8 + lh) * DO + 0 + sslot * 4,
              (void*)(&As[0][0] + m * 256));
    gld_lds16(A + (size_t)(col0 + m * 8 + lh) * DO + 0 + sslot * 4,
              (void*)(&Bs[0][0] + m * 256));
  }
  __syncthreads();

  for (int t = 0; t < DO / 32; ++t) {
    int cur = t & 1;
    if (t + 1 < DO / 32) {
      int kt = (t + 1) * 32;
#pragma unroll
      for (int c = 0; c < 2; ++c) {
        int m = wave * 2 + c;
        gld_lds16(A + (size_t)(row0 + m * 8 + lh) * DO + kt + sslot * 4,
                  (void*)(&As[cur ^ 1][0] + m * 256));
        gld_lds16(A + (size_t)(col0 + m * 8 + lh) * DO + kt + sslot * 4,
                  (void*)(&Bs[cur ^ 1][0] + m * 256));
      }
    }
    const float* Ab = &As[cur][0];
    const float* Bb = &Bs[cur][0];
#pragma unroll
    for (int kq = 0; kq < 8; ++kq) {
      float4 b4[4];
#pragma unroll
      for (int j = 0; j < 4; ++j)
        b4[j] = *(const float4*)(Bb + (tx + 16 * j) * 32 + ((kq ^ swb) << 2));
#pragma unroll
      for (int i = 0; i < 4; ++i) {
        float4 a4 = *(const float4*)(Ab + (ty + 16 * i) * 32 + ((kq ^ swa) << 2));
#pragma unroll
        for (int j = 0; j < 4; ++j) {
          acc[i][j] = fmaf(a4.x, b4[j].x, acc[i][j]);
          acc[i][j] = fmaf(a4.y, b4[j].y, acc[i][j]);
          acc[i][j] = fmaf(a4.z, b4[j].z, acc[i][j]);
          acc[i][j] = fmaf(a4.w, b4[j].w, acc[i][j]);
        }
      }
    }
    __syncthreads();
  }

  float sqi[4], sqj[4];
#pragma unroll
  for (int i = 0; i < 4; ++i) sqi[i] = sqo[row0 + ty + 16 * i];
#pragma unroll
  for (int j = 0; j < 4; ++j) sqj[j] = sqo[col0 + tx + 16 * j];
#pragma unroll
  for (int i = 0; i < 4; ++i) {
    int r = row0 + ty + 16 * i;
#pragma unroll
    for (int j = 0; j < 4; ++j) {
      int c = col0 + tx + 16 * j;
      float d = fmaxf(sqi[i] + sqj[j] - 2.0f * acc[i][j], 0.0f);
      D2[(size_t)r * NROWS + c] = d;
      D2[(size_t)c * NROWS + r] = d;          // mirror (bitwise-equal on diag tiles)
    }
  }
}

// ---------- K3: per-row top-10 (stable-sort order), wave-level merge ----------
__device__ __forceinline__ unsigned long long wave_min_u64(unsigned long long v) {
#pragma unroll
  for (int m = 32; m > 0; m >>= 1) {
    unsigned lo = __shfl_xor((unsigned)v, m);
    unsigned hi = __shfl_xor((unsigned)(v >> 32), m);
    unsigned long long o = ((unsigned long long)hi << 32) | lo;
    v = o < v ? o : v;
  }
  return v;
}

__global__ __launch_bounds__(256) void topk_k(const float* __restrict__ D2,
                                              int* __restrict__ topk) {
  int row = blockIdx.x;
  int tid = threadIdx.x;
  const float* p = D2 + (size_t)row * NROWS;

  unsigned long long lst[KNN];
#pragma unroll
  for (int t = 0; t < KNN; ++t) lst[t] = ~0ULL;

  auto consider = [&](float val, int j) {
    unsigned long long key =
        ((unsigned long long)__float_as_uint(val) << 32) | (unsigned)j;
    if (key < lst[KNN - 1]) {
      lst[KNN - 1] = key;
#pragma unroll
      for (int t = KNN - 1; t > 0; --t) {
        if (lst[t] < lst[t - 1]) {
          unsigned long long tmp = lst[t]; lst[t] = lst[t - 1]; lst[t - 1] = tmp;
        }
      }
    }
  };

#pragma unroll
  for (int s = 0; s < 4; ++s) {
    int q = tid + s * 256;
    float4 v = *(const float4*)(p + q * 4);
    consider(v.x, q * 4 + 0);
    consider(v.y, q * 4 + 1);
    consider(v.z, q * 4 + 2);
    consider(v.w, q * 4 + 3);
  }

  int lane = tid & 63, wv = tid >> 6;
  __shared__ unsigned long long wl[64];       // 4 waves * 16 slots
  for (int s = 0; s < KNN; ++s) {
    unsigned long long w = wave_min_u64(lst[0]);
    if (lst[0] == w) {                        // exactly one lane (keys unique)
#pragma unroll
      for (int t = 0; t < KNN - 1; ++t) lst[t] = lst[t + 1];
      lst[KNN - 1] = ~0ULL;
    }
    if (lane == 0) wl[wv * 16 + s] = w;
  }
  __syncthreads();
  if (wv == 0) {
    unsigned long long v = ((lane & 15) < KNN) ? wl[lane] : ~0ULL;
    for (int s = 0; s < KNN; ++s) {
      unsigned long long w = wave_min_u64(v);
      if (v == w) v = ~0ULL;
      if (lane == 0) topk[row * 16 + s] = (int)(w & 0xFFFFFFFFULL);
    }
  }
}

// ---------- K4: symmetrized anchor bitmask ----------
__global__ void build_mask_k(const int* __restrict__ topk,
                             unsigned int* __restrict__ mask) {
  int i = blockIdx.x;
  int t = threadIdx.x;
  if (t < KNN) {
    int j = topk[i * 16 + t];
    atomicOr(mask + (size_t)i * (NROWS / 32) + (j >> 5), 1u << (j & 31));
    atomicOr(mask + (size_t)j * (NROWS / 32) + (i >> 5), 1u << (i & 31));
  }
}

// ---------- K4c: popcount -> a_sum ----------
__global__ __launch_bounds__(256) void popcnt_k(const unsigned int* __restrict__ mask,
                                                int* __restrict__ a_sum) {
  int tid = blockIdx.x * 256 + threadIdx.x;
  int stride = gridDim.x * 256;
  int cnt = 0;
  for (int q = tid; q < NROWS * (NROWS / 32); q += stride) cnt += __popc(mask[q]);
  for (int off = 32; off > 0; off >>= 1) cnt += __shfl_down(cnt, off);
  __shared__ int wsum[4];
  int lane = threadIdx.x & 63, wv = threadIdx.x >> 6;
  if (lane == 0) wsum[wv] = cnt;
  __syncthreads();
  if (threadIdx.x == 0) atomicAdd(a_sum, wsum[0] + wsum[1] + wsum[2] + wsum[3]);
}

// ---------- K5: bf16 MFMA GEMM (S S^T), symmetric, 64x64 tiles, BK=64, dbuf ----------
// LDS [64][64] bf16 (128B rows, 8 slots of 16B). Slot s of row r holds
// global 8-bf16 group (r, s ^ (r&7)) -- pre-swizzled source, linear LDS.
__global__ __launch_bounds__(256) void gemm_cos_k(const bf16* __restrict__ S,
                                                  float* __restrict__ C) {
  __shared__ bf16 Asm[2][64 * 64];
  __shared__ bf16 Bsm[2][64 * 64];
  int bj = blockIdx.x, bi = blockIdx.y;
  if (bi > bj) return;
  int row0 = bi * 64, col0 = bj * 64;
  int tid = threadIdx.x;
  int wave = tid >> 6, lane = tid & 63;
  int wr = wave >> 1, wc = wave & 1;          // 2x2 waves, 32x32 each
  int lr = lane & 15, lk = lane >> 4;
  int lh = lane >> 3;
  int sslot = (lane & 7) ^ lh;                // swizzled source slot (8-bf16 units)
  int swf = lr & 7;                           // frag-read swizzle

  f32x4 acc[2][2];
#pragma unroll
  for (int m = 0; m < 2; ++m)
#pragma unroll
    for (int n = 0; n < 2; ++n) acc[m][n] = f32x4{0.f, 0.f, 0.f, 0.f};

  // prologue: stage tile 0
#pragma unroll
  for (int c = 0; c < 2; ++c) {
    int m = wave * 2 + c;                     // chunk 0..7, 8 rows each
    gld_lds16(S + (size_t)(row0 + m * 8 + lh) * DH + 0 + sslot * 8,
              (void*)(&Asm[0][0] + m * 512));
    gld_lds16(S + (size_t)(col0 + m * 8 + lh) * DH + 0 + sslot * 8,
              (void*)(&Bsm[0][0] + m * 512));
  }
  __syncthreads();

  for (int t = 0; t < DH / 64; ++t) {
    int cur = t & 1;
    if (t + 1 < DH / 64) {
      int kt = (t + 1) * 64;
#pragma unroll
      for (int c = 0; c < 2; ++c) {
        int m = wave * 2 + c;
        gld_lds16(S + (size_t)(row0 + m * 8 + lh) * DH + kt + sslot * 8,
                  (void*)(&Asm[cur ^ 1][0] + m * 512));
        gld_lds16(S + (size_t)(col0 + m * 8 + lh) * DH + kt + sslot * 8,
                  (void*)(&Bsm[cur ^ 1][0] + m * 512));
      }
    }
    const bf16* Ab = &Asm[cur][0];
    const bf16* Bb = &Bsm[cur][0];
#pragma unroll
    for (int kb = 0; kb < 2; ++kb) {
      bf16x8 af[2], bfr[2];
#pragma unroll
      for (int m = 0; m < 2; ++m) {
        int ra = wr * 32 + m * 16 + lr;
        int rb = wc * 32 + m * 16 + lr;
        af[m]  = *(const bf16x8*)(Ab + ra * 64 + (((kb * 4 + lk) ^ swf) << 3));
        bfr[m] = *(const bf16x8*)(Bb + rb * 64 + (((kb * 4 + lk) ^ swf) << 3));
      }
#pragma unroll
      for (int m = 0; m < 2; ++m)
#pragma unroll
        for (int n = 0; n < 2; ++n)
          acc[m][n] = __builtin_amdgcn_mfma_f32_16x16x32_bf16(af[m], bfr[n],
                                                              acc[m][n], 0, 0, 0);
    }
    __syncthreads();
  }

  // C/D layout: col = lane&15, row = (lane>>4)*4 + reg
#pragma unroll
  for (int m = 0; m < 2; ++m) {
#pragma unroll
    for (int n = 0; n < 2; ++n) {
      int col = col0 + wc * 32 + n * 16 + lr;
#pragma unroll
      for (int g = 0; g < 4; ++g) {
        int rrow = row0 + wr * 32 + m * 16 + lk * 4 + g;
        float v = acc[m][n][g];
        C[(size_t)rrow * NROWS + col] = v;
        C[(size_t)col * NROWS + rrow] = v;    // mirror
      }
    }
  }
}

// ---------- K6: masked scaling into both outputs (in place) ----------
__global__ __launch_bounds__(256) void finalize_k(float* __restrict__ Cm,
                                                  float* __restrict__ Aout,
                                                  const unsigned int* __restrict__ mask,
                                                  const int* __restrict__ a_sum_p) {
  size_t idx = (size_t)blockIdx.x * 256 + threadIdx.x;   // one float4 each
  int i  = (int)(idx >> 10);
  int jq = (int)(idx & 1023);
  float asum = (float)(*a_sum_p);
  float Nw = 0.5f / asum;                                 // (1-ALPHA)/a_sum
  float Nb = 1.0f / (16777216.0f - 2.0f * asum);          // 1/(N*N - 2*a_sum)
  unsigned int mw = mask[(size_t)i * (NROWS / 32) + (jq >> 3)];
  int b0 = (jq & 7) * 4;
  float4 c = ((const float4*)Cm)[idx];
  float4 na, aa;
  { unsigned a = (mw >> (b0 + 0)) & 1u; na.x = a ? 0.f : Nb * c.x; aa.x = a ? Nw * c.x : 0.f; }
  { unsigned a = (mw >> (b0 + 1)) & 1u; na.y = a ? 0.f : Nb * c.y; aa.y = a ? Nw * c.y : 0.f; }
  { unsigned a = (mw >> (b0 + 2)) & 1u; na.z = a ? 0.f : Nb * c.z; aa.z = a ? Nw * c.z : 0.f; }
  { unsigned a = (mw >> (b0 + 3)) & 1u; na.w = a ? 0.f : Nb * c.w; aa.w = a ? Nw * c.w : 0.f; }
  ((float4*)Cm)[idx]   = na;
  ((float4*)Aout)[idx] = aa;
}

extern "C" void kernel_launch(void* const* d_in, const int* in_sizes, int n_in,
                              void* d_out, int out_size, void* d_ws, size_t ws_size,
                              hipStream_t stream) {
  const float* original = (const float*)d_in[0];
  const float* hidden   = (const float*)d_in[1];
  float* out0 = (float*)d_out;                       // non_anchor_out (also C scratch)
  float* out1 = out0 + (size_t)NROWS * NROWS;        // anchor_out (also D2 scratch)

  char* ws = (char*)d_ws;
  float*        sqo   = (float*)(ws + OFF_SQO);
  int*          topk  = (int*)(ws + OFF_TOPK);
  int*          a_sum = (int*)(ws + OFF_ASUM);
  unsigned int* mask  = (unsigned int*)(ws + OFF_MASK);
  bf16*         sim   = (bf16*)(ws + OFF_SIM);

  rownorm_orig_k<<<NROWS, 256, 0, stream>>>(original, sqo);
  normalize_hidden_k<<<NROWS, 256, 0, stream>>>(hidden, sim);

  dim3 g64(NROWS / 64, NROWS / 64);
  sgemm_d2_k<<<g64, 256, 0, stream>>>(original, sqo, out1);

  topk_k<<<NROWS, 256, 0, stream>>>(out1, topk);

  hipMemsetAsync(ws + OFF_ASUM, 0, 256 + (size_t)NROWS * (NROWS / 32) * 4, stream);
  build_mask_k<<<NROWS, 64, 0, stream>>>(topk, mask);
  popcnt_k<<<512, 256, 0, stream>>>(mask, a_sum);

  gemm_cos_k<<<g64, 256, 0, stream>>>(sim, out0);

  finalize_k<<<(NROWS / 4) * (NROWS / 256), 256, 0, stream>>>(out0, out1, mask, a_sum);
}

// Round 3
// 320.767 us; speedup vs baseline: 1.4574x; 1.4492x over previous
//
#include <hip/hip_runtime.h>
#include <cstdint>
#include <cstddef>

#define NROWS 4096
#define DO 512
#define DH 1024
#define KNN 10
#define CAND 16

typedef __bf16 bf16;
typedef __bf16 bf16x2_t __attribute__((ext_vector_type(2)));
typedef __bf16 bf16x4_t __attribute__((ext_vector_type(4)));
typedef __bf16 bf16x8 __attribute__((ext_vector_type(8)));
typedef float f32x4 __attribute__((ext_vector_type(4)));
typedef unsigned long long u64;

// ---------- ws layout ----------
constexpr size_t OFF_SQO  = 0;                       // 4096 * 4      = 16384
constexpr size_t OFF_TOPK = 16384;                   // 4096 * 16 * 4 = 262144 (cand, rescored in place)
constexpr size_t OFF_ASUM = 278528;                  // 256 bytes
constexpr size_t OFF_MASK = 278784;                  // 4096 * 128 * 4 = 2097152
constexpr size_t OFF_SIM  = 2375936;                 // 4096 * 1024 * 2 = 8388608
// total ~10.8 MB  (bf16 original lives in d_out's first 4 MB until cos GEMM)

__device__ __forceinline__ void gld_lds16(const void* g, void* l) {
  __builtin_amdgcn_global_load_lds(
      (const __attribute__((address_space(1))) unsigned int*)g,
      (__attribute__((address_space(3))) unsigned int*)l, 16, 0, 0);
}

__device__ __forceinline__ u64 wave_min_u64(u64 v) {
#pragma unroll
  for (int m = 32; m > 0; m >>= 1) {
    unsigned lo = __shfl_xor((unsigned)v, m);
    unsigned hi = __shfl_xor((unsigned)(v >> 32), m);
    u64 o = ((u64)hi << 32) | lo;
    v = o < v ? o : v;
  }
  return v;
}

// ---------- K0a: row squared norms of `original` + bf16 copy ----------
__global__ __launch_bounds__(256) void rownorm_orig_k(const float* __restrict__ x,
                                                      float* __restrict__ sqo,
                                                      bf16* __restrict__ abf) {
  int row = blockIdx.x;
  int tid = threadIdx.x;
  float2 v = ((const float2*)(x + (size_t)row * DO))[tid];
  bf16x2_t o; o[0] = (bf16)v.x; o[1] = (bf16)v.y;
  ((bf16x2_t*)(abf + (size_t)row * DO))[tid] = o;
  float s = v.x * v.x + v.y * v.y;
  __shared__ float red[256];
  red[tid] = s; __syncthreads();
  for (int off = 128; off > 0; off >>= 1) {
    if (tid < off) red[tid] += red[tid + off];
    __syncthreads();
  }
  if (tid == 0) sqo[row] = red[0];
}

// ---------- K0b: normalize `hidden` rows -> bf16 sim matrix ----------
__global__ __launch_bounds__(256) void normalize_hidden_k(const float* __restrict__ h,
                                                          bf16* __restrict__ sim) {
  int row = blockIdx.x;
  int tid = threadIdx.x;
  float4 v = ((const float4*)(h + (size_t)row * DH))[tid];
  float s = v.x * v.x + v.y * v.y + v.z * v.z + v.w * v.w;
  __shared__ float red[256];
  red[tid] = s; __syncthreads();
  for (int off = 128; off > 0; off >>= 1) {
    if (tid < off) red[tid] += red[tid + off];
    __syncthreads();
  }
  float scale = 1.0f / fmaxf(sqrtf(red[0]), 1e-12f);
  bf16x4_t o;
  o[0] = (bf16)(v.x * scale);
  o[1] = (bf16)(v.y * scale);
  o[2] = (bf16)(v.z * scale);
  o[3] = (bf16)(v.w * scale);
  ((bf16x4_t*)(sim + (size_t)row * DH))[tid] = o;
}

// ---------- K1: bf16 MFMA GEMM -> approx squared distances (m97 structure) ----------
// 128x128 tile, BK=32, 4 waves 2x2, 4x4 frags of 16x16x32. Linear LDS [128][32].
__global__ __launch_bounds__(256) void d2approx_k(const bf16* __restrict__ Ab,
                                                  const float* __restrict__ sqo,
                                                  float* __restrict__ D2) {
  __shared__ bf16 Asm[128 * 32];
  __shared__ bf16 Bsm[128 * 32];
  int id = blockIdx.x;
  int swz = (id & 7) * 128 + (id >> 3);        // XCD-aware swizzle (1024 % 8 == 0)
  int bi = swz >> 5, bj = swz & 31;
  int row0 = bi * 128, col0 = bj * 128;
  int tid = threadIdx.x, wave = tid >> 6, lane = tid & 63;
  int wr = wave >> 1, wc = wave & 1;
  int lr = lane & 15, lk = lane >> 4;

  f32x4 acc[4][4];
#pragma unroll
  for (int m = 0; m < 4; ++m)
#pragma unroll
    for (int n = 0; n < 4; ++n) acc[m][n] = f32x4{0.f, 0.f, 0.f, 0.f};

  for (int kt = 0; kt < DO; kt += 32) {
#pragma unroll
    for (int s = 0; s < 2; ++s) {
      int chunk = s * 256 + tid;               // 16B chunk id, 512 per matrix
      int r = chunk >> 2, ks = chunk & 3;
      bf16* baseA = Asm + (size_t)(s * 256 + wave * 64) * 8;  // wave-uniform dest
      bf16* baseB = Bsm + (size_t)(s * 256 + wave * 64) * 8;
      gld_lds16(Ab + (size_t)(row0 + r) * DO + kt + ks * 8, baseA);
      gld_lds16(Ab + (size_t)(col0 + r) * DO + kt + ks * 8, baseB);
    }
    __syncthreads();
    bf16x8 af[4], bfr[4];
#pragma unroll
    for (int m = 0; m < 4; ++m) {
      af[m]  = *(const bf16x8*)&Asm[(wr * 64 + m * 16 + lr) * 32 + lk * 8];
      bfr[m] = *(const bf16x8*)&Bsm[(wc * 64 + m * 16 + lr) * 32 + lk * 8];
    }
#pragma unroll
    for (int m = 0; m < 4; ++m)
#pragma unroll
      for (int n = 0; n < 4; ++n)
        acc[m][n] = __builtin_amdgcn_mfma_f32_16x16x32_bf16(af[m], bfr[n],
                                                            acc[m][n], 0, 0, 0);
    __syncthreads();
  }

  float sqc[4];
#pragma unroll
  for (int n = 0; n < 4; ++n) sqc[n] = sqo[col0 + wc * 64 + n * 16 + lr];
#pragma unroll
  for (int m = 0; m < 4; ++m) {
#pragma unroll
    for (int g = 0; g < 4; ++g) {
      int row = row0 + wr * 64 + m * 16 + lk * 4 + g;
      float sr = sqo[row];
      float* dst = D2 + (size_t)row * NROWS + col0 + wc * 64 + lr;
#pragma unroll
      for (int n = 0; n < 4; ++n)
        dst[n * 16] = fmaxf(sr + sqc[n] - 2.0f * acc[m][n][g], 0.0f);
    }
  }
}

// ---------- K2: per-row approx top-16 candidates ----------
__global__ __launch_bounds__(256) void topk_k(const float* __restrict__ D2,
                                              int* __restrict__ cand) {
  int row = blockIdx.x;
  int tid = threadIdx.x;
  const float* p = D2 + (size_t)row * NROWS;

  u64 lst[CAND];
#pragma unroll
  for (int t = 0; t < CAND; ++t) lst[t] = ~0ULL;

  auto consider = [&](float val, int j) {
    u64 key = ((u64)__float_as_uint(val) << 32) | (unsigned)j;
    if (key < lst[CAND - 1]) {
      lst[CAND - 1] = key;
#pragma unroll
      for (int t = CAND - 1; t > 0; --t) {
        if (lst[t] < lst[t - 1]) { u64 tmp = lst[t]; lst[t] = lst[t - 1]; lst[t - 1] = tmp; }
      }
    }
  };

#pragma unroll
  for (int s = 0; s < 4; ++s) {
    int q = tid + s * 256;
    float4 v = *(const float4*)(p + q * 4);
    consider(v.x, q * 4 + 0);
    consider(v.y, q * 4 + 1);
    consider(v.z, q * 4 + 2);
    consider(v.w, q * 4 + 3);
  }

  int lane = tid & 63, wv = tid >> 6;
  __shared__ u64 wl[64];                       // 4 waves * 16
  for (int s = 0; s < CAND; ++s) {
    u64 w = wave_min_u64(lst[0]);
    if (lst[0] == w) {                         // unique keys -> exactly one lane
#pragma unroll
      for (int t = 0; t < CAND - 1; ++t) lst[t] = lst[t + 1];
      lst[CAND - 1] = ~0ULL;
    }
    if (lane == 0) wl[wv * 16 + s] = w;
  }
  __syncthreads();
  if (wv == 0) {
    u64 v = wl[lane];
    for (int s = 0; s < CAND; ++s) {
      u64 w = wave_min_u64(v);
      if (v == w) v = ~0ULL;
      if (lane == 0) cand[row * 16 + s] = (int)(w & 0xFFFFFFFFULL);
    }
  }
}

// ---------- K3: exact fp64-accum rescore of 16 candidates -> top-10 ----------
__global__ __launch_bounds__(256) void rescore_k(const float* __restrict__ A,
                                                 const float* __restrict__ sqo,
                                                 int* __restrict__ cand) {
  int row = blockIdx.x;
  int tid = threadIdx.x;
  int wave = tid >> 6, lane = tid & 63;
  __shared__ float xi[DO];
  __shared__ int cnd[CAND];
  __shared__ u64 keys[CAND];
  ((float2*)xi)[tid] = ((const float2*)(A + (size_t)row * DO))[tid];
  if (tid < CAND) cnd[tid] = cand[row * 16 + tid];
  __syncthreads();

  int g = lane >> 4;                           // 4 cands per wave
  int c = cnd[wave * 4 + g];
  int seg = lane & 15;                         // 32 dims per lane
  const float* xc = A + (size_t)c * DO + seg * 32;
  const float* xr = xi + seg * 32;
  double dot = 0.0;
#pragma unroll
  for (int q = 0; q < 8; ++q) {
    int qq = (q + seg) & 7;                    // rotated to dodge LDS bank conflicts
    float4 a = *(const float4*)(xr + qq * 4);
    float4 b = *(const float4*)(xc + qq * 4);
    dot = fma((double)a.x, (double)b.x, dot);
    dot = fma((double)a.y, (double)b.y, dot);
    dot = fma((double)a.z, (double)b.z, dot);
    dot = fma((double)a.w, (double)b.w, dot);
  }
#pragma unroll
  for (int m2 = 1; m2 < 16; m2 <<= 1) dot += __shfl_xor(dot, m2);
  if (seg == 0) {
    double d2 = (double)sqo[row] + (double)sqo[c] - 2.0 * dot;
    float d2f = (float)fmax(d2, 0.0);
    keys[wave * 4 + g] = ((u64)__float_as_uint(d2f) << 32) | (unsigned)c;
  }
  __syncthreads();
  if (wave == 0) {
    u64 v = (lane < CAND) ? keys[lane] : ~0ULL;
    for (int s = 0; s < KNN; ++s) {
      u64 w = wave_min_u64(v);
      if (v == w) v = ~0ULL;
      if (lane == 0) cand[row * 16 + s] = (int)(w & 0xFFFFFFFFULL);
    }
  }
}

// ---------- K4: symmetrized anchor bitmask ----------
__global__ void build_mask_k(const int* __restrict__ topk,
                             unsigned int* __restrict__ mask) {
  int i = blockIdx.x;
  int t = threadIdx.x;
  if (t < KNN) {
    int j = topk[i * 16 + t];
    atomicOr(mask + (size_t)i * (NROWS / 32) + (j >> 5), 1u << (j & 31));
    atomicOr(mask + (size_t)j * (NROWS / 32) + (i >> 5), 1u << (i & 31));
  }
}

// ---------- K4c: popcount -> a_sum ----------
__global__ __launch_bounds__(256) void popcnt_k(const unsigned int* __restrict__ mask,
                                                int* __restrict__ a_sum) {
  int tid = blockIdx.x * 256 + threadIdx.x;
  int stride = gridDim.x * 256;
  int cnt = 0;
  for (int q = tid; q < NROWS * (NROWS / 32); q += stride) cnt += __popc(mask[q]);
  for (int off = 32; off > 0; off >>= 1) cnt += __shfl_down(cnt, off);
  __shared__ int wsum[4];
  int lane = threadIdx.x & 63, wv = threadIdx.x >> 6;
  if (lane == 0) wsum[wv] = cnt;
  __syncthreads();
  if (threadIdx.x == 0) atomicAdd(a_sum, wsum[0] + wsum[1] + wsum[2] + wsum[3]);
}

// ---------- K5: bf16 MFMA cosine GEMM + fused finalize epilogue ----------
__global__ __launch_bounds__(256) void gemm_cos_fused_k(const bf16* __restrict__ S,
                                                        const unsigned int* __restrict__ mask,
                                                        const int* __restrict__ a_sum_p,
                                                        float* __restrict__ out0,
                                                        float* __restrict__ out1) {
  __shared__ bf16 Asm[128 * 32];
  __shared__ bf16 Bsm[128 * 32];
  int id = blockIdx.x;
  int swz = (id & 7) * 128 + (id >> 3);
  int bi = swz >> 5, bj = swz & 31;
  int row0 = bi * 128, col0 = bj * 128;
  int tid = threadIdx.x, wave = tid >> 6, lane = tid & 63;
  int wr = wave >> 1, wc = wave & 1;
  int lr = lane & 15, lk = lane >> 4;

  f32x4 acc[4][4];
#pragma unroll
  for (int m = 0; m < 4; ++m)
#pragma unroll
    for (int n = 0; n < 4; ++n) acc[m][n] = f32x4{0.f, 0.f, 0.f, 0.f};

  for (int kt = 0; kt < DH; kt += 32) {
#pragma unroll
    for (int s = 0; s < 2; ++s) {
      int chunk = s * 256 + tid;
      int r = chunk >> 2, ks = chunk & 3;
      bf16* baseA = Asm + (size_t)(s * 256 + wave * 64) * 8;
      bf16* baseB = Bsm + (size_t)(s * 256 + wave * 64) * 8;
      gld_lds16(S + (size_t)(row0 + r) * DH + kt + ks * 8, baseA);
      gld_lds16(S + (size_t)(col0 + r) * DH + kt + ks * 8, baseB);
    }
    __syncthreads();
    bf16x8 af[4], bfr[4];
#pragma unroll
    for (int m = 0; m < 4; ++m) {
      af[m]  = *(const bf16x8*)&Asm[(wr * 64 + m * 16 + lr) * 32 + lk * 8];
      bfr[m] = *(const bf16x8*)&Bsm[(wc * 64 + m * 16 + lr) * 32 + lk * 8];
    }
#pragma unroll
    for (int m = 0; m < 4; ++m)
#pragma unroll
      for (int n = 0; n < 4; ++n)
        acc[m][n] = __builtin_amdgcn_mfma_f32_16x16x32_bf16(af[m], bfr[n],
                                                            acc[m][n], 0, 0, 0);
    __syncthreads();
  }

  // stage this tile's mask slice (128 rows x 4 words) into LDS (reuse Asm)
  unsigned* lmask = (unsigned*)Asm;
  {
    int w0 = tid;
    lmask[w0] = mask[(size_t)(row0 + (w0 >> 2)) * 128 + bj * 4 + (w0 & 3)];
    int w1 = tid + 256;
    lmask[w1] = mask[(size_t)(row0 + (w1 >> 2)) * 128 + bj * 4 + (w1 & 3)];
  }
  __syncthreads();

  float asum = (float)(*a_sum_p);
  float Nw = 0.5f / asum;                      // (1-ALPHA)/a_sum
  float Nb = 1.0f / (16777216.0f - 2.0f * asum);

#pragma unroll
  for (int m = 0; m < 4; ++m) {
#pragma unroll
    for (int g = 0; g < 4; ++g) {
      int rl = wr * 64 + m * 16 + lk * 4 + g;
      size_t rowoff = (size_t)(row0 + rl) * NROWS;
#pragma unroll
      for (int n = 0; n < 4; ++n) {
        int cl = wc * 64 + n * 16 + lr;
        unsigned wbit = lmask[rl * 4 + (cl >> 5)];
        unsigned a = (wbit >> (cl & 31)) & 1u;
        float cv = acc[m][n][g];
        out0[rowoff + col0 + cl] = a ? 0.0f : Nb * cv;
        out1[rowoff + col0 + cl] = a ? Nw * cv : 0.0f;
      }
    }
  }
}

extern "C" void kernel_launch(void* const* d_in, const int* in_sizes, int n_in,
                              void* d_out, int out_size, void* d_ws, size_t ws_size,
                              hipStream_t stream) {
  const float* original = (const float*)d_in[0];
  const float* hidden   = (const float*)d_in[1];
  float* out0 = (float*)d_out;                       // non_anchor_out
  float* out1 = out0 + (size_t)NROWS * NROWS;        // anchor_out (approx-D2 scratch first)
  bf16*  Ab   = (bf16*)out0;                         // bf16 original (4 MB scratch in out0)

  char* ws = (char*)d_ws;
  float*        sqo   = (float*)(ws + OFF_SQO);
  int*          cand  = (int*)(ws + OFF_TOPK);
  int*          a_sum = (int*)(ws + OFF_ASUM);
  unsigned int* mask  = (unsigned int*)(ws + OFF_MASK);
  bf16*         sim   = (bf16*)(ws + OFF_SIM);

  rownorm_orig_k<<<NROWS, 256, 0, stream>>>(original, sqo, Ab);
  normalize_hidden_k<<<NROWS, 256, 0, stream>>>(hidden, sim);
  hipMemsetAsync(ws + OFF_ASUM, 0, 256 + (size_t)NROWS * (NROWS / 32) * 4, stream);

  d2approx_k<<<1024, 256, 0, stream>>>(Ab, sqo, out1);
  topk_k<<<NROWS, 256, 0, stream>>>(out1, cand);
  rescore_k<<<NROWS, 256, 0, stream>>>(original, sqo, cand);

  build_mask_k<<<NROWS, 64, 0, stream>>>(cand, mask);
  popcnt_k<<<512, 256, 0, stream>>>(mask, a_sum);

  gemm_cos_fused_k<<<1024, 256, 0, stream>>>(sim, mask, a_sum, out0, out1);
}